// Round 1
// baseline (953.354 us; speedup 1.0000x reference)
//
#include <hip/hip_runtime.h>
#include <hip/hip_bf16.h>
#include <math.h>

// Problem constants (from reference setup_inputs)
#define NB 2
#define SEQ 2048
#define NH 16
#define DNOPE 128
#define DROT 64
#define DVDIM 128
#define BM 64
#define BN 64
// LDS strides (elements) chosen for bank-conflict behavior:
//  K: 200 elems = 400 B -> row step 100 dw % 32 = 4 banks -> 2-way (free), 16B aligned
//  V/P: 72 elems = 144 B -> 36 dw % 32 = 4 -> 2-way (free), 16B aligned
#define KST 200
#define VST 72
#define PST 72

typedef __bf16 bf16x8_t __attribute__((ext_vector_type(8)));
typedef __bf16 bf16x4_t __attribute__((ext_vector_type(4)));
typedef __bf16 bf16x2_t __attribute__((ext_vector_type(2)));
typedef float f32x4_t __attribute__((ext_vector_type(4)));

// log2(10000)/32 — inv_freq_i = 2^(-i * this)
#define LOG2_BASE_OVER_HALFDIM 0.41524101186092028f

// ---------------------------------------------------------------------------
// Pre-kernel: rope k_pe (B,S,1,64) fp32 -> bf16 into workspace.
// YaRN collapses to plain RoPE because SCALING_FACTOR==1 (mask cancels, _m==1).
// ---------------------------------------------------------------------------
__global__ __launch_bounds__(256) void rope_k_kernel(
    const float* __restrict__ k_pe, __bf16* __restrict__ kp_out)
{
  int idx = blockIdx.x * 256 + threadIdx.x;     // over NB*SEQ*DROT = 262144
  int dr  = idx & (DROT - 1);
  int row = idx >> 6;                            // b*SEQ + n
  int n   = row & (SEQ - 1);                     // position in sequence
  int i   = dr & 31;
  float invf = exp2f(-LOG2_BASE_OVER_HALFDIM * (float)i);
  float ang  = (float)n * invf;
  float c = cosf(ang), s = sinf(ang);
  float x = k_pe[(size_t)row * DROT + dr];
  float other = (dr < 32) ? -k_pe[(size_t)row * DROT + dr + 32]
                          :  k_pe[(size_t)row * DROT + dr - 32];
  kp_out[idx] = (__bf16)(x * c + other * s);
}

// ---------------------------------------------------------------------------
// Flash-attention forward. 1 WG = 4 waves; wave w owns q-rows [qb+16w, qb+16w+16).
// MFMA 16x16x32 bf16. Layouts (HW-verified per guide m89/m91/m120):
//   A-frag: A[m=lane&15][k=quad*8+j]   B-frag: B[k=quad*8+j][n=lane&15]
//   C/D:    row=quad*4+reg, col=lane&15
// ---------------------------------------------------------------------------
__global__ __launch_bounds__(256) void mla_fwd_kernel(
    const float* __restrict__ q_nope, const float* __restrict__ q_pe,
    const float* __restrict__ k_nope, const __bf16* __restrict__ kp,
    const float* __restrict__ v,
    float* __restrict__ out_o, float* __restrict__ out_lse)
{
  __shared__ __bf16 Kl[BN * KST];        // 25600 B : K tile, rows n, 192 cols
  __shared__ __bf16 Vt[DVDIM * VST];     // 18432 B : V tile transposed [dv][n], swizzled
  __shared__ __bf16 Pl[4 * 16 * PST];    //  9216 B : per-wave P transpose buffer

  const int qt   = (int)gridDim.x - 1 - (int)blockIdx.x;  // reverse: big tiles first
  const int h    = blockIdx.y;
  const int b    = blockIdx.z;
  const int qb   = qt * BM;
  const int tid  = threadIdx.x;
  const int w    = tid >> 6;
  const int lane = tid & 63;
  const int col  = lane & 15;
  const int quad = lane >> 4;

  // ---- Q fragments (A-layout); rope applied to chunks 4,5 (k = 128..191)
  const int mrow = qb + w * 16 + col;    // this lane's A-operand row (= position)
  const float* qn = q_nope + (size_t)((b * SEQ + mrow) * NH + h) * DNOPE;
  const float* qp = q_pe   + (size_t)((b * SEQ + mrow) * NH + h) * DROT;

  bf16x8_t qfrag[6];
#pragma unroll
  for (int c = 0; c < 4; ++c) {
    const float* p = qn + c * 32 + quad * 8;
    float4 a  = *(const float4*)p;
    float4 bq = *(const float4*)(p + 4);
    bf16x8_t f;
    f[0]=(__bf16)a.x;  f[1]=(__bf16)a.y;  f[2]=(__bf16)a.z;  f[3]=(__bf16)a.w;
    f[4]=(__bf16)bq.x; f[5]=(__bf16)bq.y; f[6]=(__bf16)bq.z; f[7]=(__bf16)bq.w;
    qfrag[c] = f;
  }
  {
    const float* plo = qp + quad * 8;
    const float* phi = qp + 32 + quad * 8;
    float4 lo0 = *(const float4*)plo;
    float4 lo1 = *(const float4*)(plo + 4);
    float4 hi0 = *(const float4*)phi;
    float4 hi1 = *(const float4*)(phi + 4);
    float xl[8] = {lo0.x,lo0.y,lo0.z,lo0.w,lo1.x,lo1.y,lo1.z,lo1.w};
    float xh[8] = {hi0.x,hi0.y,hi0.z,hi0.w,hi1.x,hi1.y,hi1.z,hi1.w};
    bf16x8_t f4v, f5v;
#pragma unroll
    for (int j = 0; j < 8; ++j) {
      int i = quad * 8 + j;
      float invf = exp2f(-LOG2_BASE_OVER_HALFDIM * (float)i);
      float ang  = (float)mrow * invf;
      float cc = cosf(ang), ss = sinf(ang);
      f4v[j] = (__bf16)(xl[j] * cc - xh[j] * ss);   // dr = i      (first half)
      f5v[j] = (__bf16)(xh[j] * cc + xl[j] * ss);   // dr = i + 32 (second half)
    }
    qfrag[4] = f4v; qfrag[5] = f5v;
  }

  f32x4_t oacc[8];
#pragma unroll
  for (int i = 0; i < 8; ++i) oacc[i] = (f32x4_t){0.f, 0.f, 0.f, 0.f};
  float m_run[4] = {-INFINITY, -INFINITY, -INFINITY, -INFINITY};
  float l_run[4] = {0.f, 0.f, 0.f, 0.f};

  const float kSL2 = 0.07216878364870322f * 1.4426950408889634f; // 192^-0.5 * log2e

  const int ntiles = qt + 1;            // causal: k-tiles 0..qt
  for (int it = 0; it < ntiles; ++it) {
    const int kb = it * BN;
    __syncthreads();                    // protect LDS from previous iteration's readers

    // ---- stage K nope: 64 rows x 128 cols fp32 -> bf16 (coalesced float4 reads)
#pragma unroll
    for (int t2 = 0; t2 < 8; ++t2) {
      int task = tid + t2 * 256;
      int n = task >> 5, f4 = task & 31;
      const float* p = k_nope + (size_t)((b * SEQ + kb + n) * NH + h) * DNOPE + f4 * 4;
      float4 a = *(const float4*)p;
      bf16x4_t bv; bv[0]=(__bf16)a.x; bv[1]=(__bf16)a.y; bv[2]=(__bf16)a.z; bv[3]=(__bf16)a.w;
      *(bf16x4_t*)&Kl[n * KST + f4 * 4] = bv;
    }
    // ---- stage K rope part (already bf16 in ws)
#pragma unroll
    for (int t2 = 0; t2 < 2; ++t2) {
      int task = tid + t2 * 256;
      int n = task >> 3, c8 = task & 7;
      bf16x8_t vv = *(const bf16x8_t*)(kp + (size_t)(b * SEQ + kb + n) * DROT + c8 * 8);
      *(bf16x8_t*)&Kl[n * KST + 128 + c8 * 8] = vv;
    }
    // ---- stage V transposed: Vt[dv][n], 16B-block XOR swizzle on n-blocks.
    // Element offset(dv,n) = dv*VST + (((n>>3) ^ ((dv>>2)&7))<<3) + (n&7)
#pragma unroll
    for (int t2 = 0; t2 < 4; ++t2) {
      int task = tid + t2 * 256;
      int np = task >> 5, f4 = task & 31;
      int n0 = np * 2;
      const float* p0 = v + (size_t)((b * SEQ + kb + n0) * NH + h) * DVDIM + f4 * 4;
      float4 a0 = *(const float4*)p0;
      float4 a1 = *(const float4*)(p0 + NH * DVDIM);   // row n0+1
      float e0[4] = {a0.x, a0.y, a0.z, a0.w};
      float e1[4] = {a1.x, a1.y, a1.z, a1.w};
#pragma unroll
      for (int e = 0; e < 4; ++e) {
        int dv  = f4 * 4 + e;
        int blk = (n0 >> 3) ^ ((dv >> 2) & 7);
        bf16x2_t pr; pr[0] = (__bf16)e0[e]; pr[1] = (__bf16)e1[e];
        *(bf16x2_t*)&Vt[dv * VST + (blk << 3) + (n0 & 7)] = pr;
      }
    }
    __syncthreads();

    // ---- S = Q K^T : 4 n-tiles of 16, K-dim 192 = 6 chunks
    f32x4_t sacc[4];
#pragma unroll
    for (int t = 0; t < 4; ++t) sacc[t] = (f32x4_t){0.f, 0.f, 0.f, 0.f};
#pragma unroll
    for (int t = 0; t < 4; ++t) {
#pragma unroll
      for (int c = 0; c < 6; ++c) {
        bf16x8_t kf = *(const bf16x8_t*)&Kl[(t * 16 + col) * KST + c * 32 + quad * 8];
        sacc[t] = __builtin_amdgcn_mfma_f32_16x16x32_bf16(qfrag[c], kf, sacc[t], 0, 0, 0);
      }
    }

    // ---- online softmax in log2 domain
    const bool diag = (it == qt);
    float pv[4][4];
    float alpha[4];
#pragma unroll
    for (int r = 0; r < 4; ++r) {
      float mx = -INFINITY;
#pragma unroll
      for (int t = 0; t < 4; ++t) {
        float sv = sacc[t][r] * kSL2;
        if (diag) {
          int nn = kb + t * 16 + col;
          int mm = qb + w * 16 + quad * 4 + r;
          if (nn > mm) sv = -INFINITY;
        }
        pv[t][r] = sv;
        mx = fmaxf(mx, sv);
      }
      mx = fmaxf(mx, __shfl_xor(mx, 1, 64));
      mx = fmaxf(mx, __shfl_xor(mx, 2, 64));
      mx = fmaxf(mx, __shfl_xor(mx, 4, 64));
      mx = fmaxf(mx, __shfl_xor(mx, 8, 64));
      float mnew = fmaxf(m_run[r], mx);
      alpha[r] = exp2f(m_run[r] - mnew);   // first tile: exp2(-inf)=0
      m_run[r] = mnew;
      float rs = 0.f;
#pragma unroll
      for (int t = 0; t < 4; ++t) {
        float p = exp2f(pv[t][r] - mnew);
        pv[t][r] = p;
        rs += p;
      }
      rs += __shfl_xor(rs, 1, 64);
      rs += __shfl_xor(rs, 2, 64);
      rs += __shfl_xor(rs, 4, 64);
      rs += __shfl_xor(rs, 8, 64);
      l_run[r] = l_run[r] * alpha[r] + rs;
    }
#pragma unroll
    for (int d = 0; d < 8; ++d) {
      f32x4_t o = oacc[d];
      o[0] *= alpha[0]; o[1] *= alpha[1]; o[2] *= alpha[2]; o[3] *= alpha[3];
      oacc[d] = o;
    }

    // ---- P: C-layout regs -> bf16 LDS -> A-layout frags (same wave, no barrier)
    __bf16* Pw = &Pl[w * 16 * PST];
#pragma unroll
    for (int t = 0; t < 4; ++t)
#pragma unroll
      for (int r = 0; r < 4; ++r)
        Pw[(quad * 4 + r) * PST + t * 16 + col] = (__bf16)pv[t][r];

    bf16x8_t pf0 = *(const bf16x8_t*)&Pw[col * PST + quad * 8];
    bf16x8_t pf1 = *(const bf16x8_t*)&Pw[col * PST + 32 + quad * 8];

    // ---- O += P V : 8 dv-tiles, K-dim 64 = 2 chunks
#pragma unroll
    for (int d = 0; d < 8; ++d) {
      int dv = d * 16 + col;
      int sw = (dv >> 2) & 7;
      bf16x8_t vf0 = *(const bf16x8_t*)&Vt[dv * VST + ((quad ^ sw) << 3)];
      bf16x8_t vf1 = *(const bf16x8_t*)&Vt[dv * VST + (((4 + quad) ^ sw) << 3)];
      oacc[d] = __builtin_amdgcn_mfma_f32_16x16x32_bf16(pf0, vf0, oacc[d], 0, 0, 0);
      oacc[d] = __builtin_amdgcn_mfma_f32_16x16x32_bf16(pf1, vf1, oacc[d], 0, 0, 0);
    }
  }

  // ---- epilogue: O /= l, write o (fp32) and lse = m + log2(l)
  float inv_l[4];
#pragma unroll
  for (int r = 0; r < 4; ++r) inv_l[r] = 1.0f / l_run[r];
#pragma unroll
  for (int d = 0; d < 8; ++d) {
#pragma unroll
    for (int r = 0; r < 4; ++r) {
      int mm = qb + w * 16 + quad * 4 + r;
      out_o[(size_t)((b * SEQ + mm) * NH + h) * DVDIM + d * 16 + col] = oacc[d][r] * inv_l[r];
    }
  }
  if (col < 4) {
    int r = col;
    int mm = qb + w * 16 + quad * 4 + r;
    out_lse[(size_t)(b * SEQ + mm) * NH + h] = m_run[r] + log2f(l_run[r]);
  }
}

// ---------------------------------------------------------------------------
extern "C" void kernel_launch(void* const* d_in, const int* in_sizes, int n_in,
                              void* d_out, int out_size, void* d_ws, size_t ws_size,
                              hipStream_t stream) {
  const float* q_nope = (const float*)d_in[0];
  const float* q_pe   = (const float*)d_in[1];
  const float* k_nope = (const float*)d_in[2];
  const float* k_pe   = (const float*)d_in[3];
  const float* v      = (const float*)d_in[4];
  float* out_o   = (float*)d_out;
  float* out_lse = out_o + (size_t)NB * SEQ * NH * DVDIM;
  __bf16* kp = (__bf16*)d_ws;   // NB*SEQ*DROT bf16 = 512 KB

  rope_k_kernel<<<dim3(NB * SEQ * DROT / 256), dim3(256), 0, stream>>>(k_pe, kp);
  mla_fwd_kernel<<<dim3(SEQ / BM, NH, NB), dim3(256), 0, stream>>>(
      q_nope, q_pe, k_nope, kp, v, out_o, out_lse);
}

// Round 2
// 316.467 us; speedup vs baseline: 3.0125x; 3.0125x over previous
//
#include <hip/hip_runtime.h>
#include <hip/hip_bf16.h>
#include <math.h>

// Problem constants (from reference setup_inputs)
#define NB 2
#define SEQ 2048
#define NH 16
#define DNOPE 128
#define DROT 64
#define DVDIM 128
#define DQK 192
#define BM 64
#define BN 64

typedef __bf16 bf16x8_t __attribute__((ext_vector_type(8)));
typedef float f32x4_t __attribute__((ext_vector_type(4)));

// log2(10000)/32 — inv_freq_i = 2^(-i * this); YaRN collapses (SCALING_FACTOR==1)
#define LOG2_BASE_OVER_HALFDIM 0.41524101186092028f

// ws layout
#define TAB_BYTES   (SEQ * 32 * sizeof(float2))            // 524288
#define KBF_ELEMS   ((size_t)NB * NH * SEQ * DQK)          // 12,582,912
#define VTB_ELEMS   ((size_t)NB * NH * DVDIM * SEQ)        //  8,388,608

// direct global->LDS DMA, 16 B per lane; LDS dest must be wave-uniform base
// (HW adds lane*16) — swizzle is therefore folded into the GLOBAL source idx.
__device__ __forceinline__ void load_lds16(const __bf16* g, __bf16* l) {
  __builtin_amdgcn_global_load_lds(
      (const __attribute__((address_space(1))) unsigned int*)g,
      (__attribute__((address_space(3))) unsigned int*)l, 16, 0, 0);
}

// ---------------------------------------------------------------------------
// cos/sin table [s][i], i<32. fp32 product (matches np outer) then fp64 trig.
// ---------------------------------------------------------------------------
__global__ __launch_bounds__(256) void trig_kernel(float2* __restrict__ tab) {
  int idx = blockIdx.x * 256 + threadIdx.x;   // 65536
  int n = idx >> 5, i = idx & 31;
  float invf = exp2f(-LOG2_BASE_OVER_HALFDIM * (float)i);
  float angf = (float)((double)n * (double)invf);  // exact fp32-rounded product
  double ang = (double)angf;
  tab[idx] = make_float2((float)cos(ang), (float)sin(ang));
}

// ---------------------------------------------------------------------------
// K prep: bf16 [b][h][s][192] = concat(k_nope, rope(k_pe)) head-major.
// ---------------------------------------------------------------------------
__global__ __launch_bounds__(256) void prep_k_kernel(
    const float* __restrict__ k_nope, const float* __restrict__ k_pe,
    const float2* __restrict__ tab, __bf16* __restrict__ Kbf) {
  int gid = blockIdx.x * 256 + threadIdx.x;   // 1,572,864 threads, 8 elems each
  size_t o8 = (size_t)gid * 8;
  int d0 = (int)(o8 % DQK);                   // multiple of 8
  int rest = (int)(o8 / DQK);                 // (b*16+h)*2048 + s
  int s = rest & (SEQ - 1);
  int bh = rest >> 11;
  int h = bh & (NH - 1), b = bh >> 4;
  bf16x8_t o;
  if (d0 < DNOPE) {
    const float* p = k_nope + ((size_t)((b * SEQ + s) * NH + h)) * DNOPE + d0;
    float4 a = *(const float4*)p;
    float4 c = *(const float4*)(p + 4);
    o[0] = (__bf16)a.x; o[1] = (__bf16)a.y; o[2] = (__bf16)a.z; o[3] = (__bf16)a.w;
    o[4] = (__bf16)c.x; o[5] = (__bf16)c.y; o[6] = (__bf16)c.z; o[7] = (__bf16)c.w;
  } else {
    int dr0 = d0 - DNOPE;
    const float* p = k_pe + (size_t)(b * SEQ + s) * DROT;
#pragma unroll
    for (int j = 0; j < 8; ++j) {
      int dr = dr0 + j;
      float2 cs = tab[s * 32 + (dr & 31)];
      float x = p[dr];
      float oth = (dr < 32) ? -p[dr + 32] : p[dr - 32];
      o[j] = (__bf16)(x * cs.x + oth * cs.y);
    }
  }
  *(bf16x8_t*)&Kbf[o8] = o;
}

// ---------------------------------------------------------------------------
// V prep: bf16 transposed [b][h][dv][s] via LDS tile.
// ---------------------------------------------------------------------------
__global__ __launch_bounds__(256) void prep_v_kernel(
    const float* __restrict__ v, __bf16* __restrict__ Vtb) {
  __shared__ __bf16 T[64][130];
  const int s0 = blockIdx.x * 64, h = blockIdx.y, b = blockIdx.z;
  const int tid = threadIdx.x;
#pragma unroll
  for (int r = 0; r < 8; ++r) {
    int task = tid + r * 256;                 // 0..2047
    int srow = task >> 5, c4 = (task & 31) * 4;
    const float* p = v + ((size_t)((b * SEQ + s0 + srow) * NH + h)) * DVDIM + c4;
    float4 a = *(const float4*)p;
    T[srow][c4 + 0] = (__bf16)a.x; T[srow][c4 + 1] = (__bf16)a.y;
    T[srow][c4 + 2] = (__bf16)a.z; T[srow][c4 + 3] = (__bf16)a.w;
  }
  __syncthreads();
#pragma unroll
  for (int r = 0; r < 4; ++r) {
    int task = tid + r * 256;                 // 0..1023
    int dv = task >> 3, c8 = (task & 7) * 8;
    bf16x8_t o;
#pragma unroll
    for (int u = 0; u < 8; ++u) o[u] = T[c8 + u][dv];
    *(bf16x8_t*)&Vtb[((size_t)(b * NH + h) * DVDIM + dv) * SEQ + s0 + c8] = o;
  }
}

// ---------------------------------------------------------------------------
// Flash attention fwd. Grid (16, NH, NB): WG bx handles q-tile pair
// {31-bx, bx} -> exactly 33 k-iterations per WG (perfect balance).
// 4 waves; wave w owns q-rows [qb+16w, qb+16w+16). mfma 16x16x32 bf16.
// LDS tiles stored as 16B blocks with XOR swizzle: K block(n,j) at
// n*24 + (j&~7)|((j&7)^(n&7)); V block(dv,j) at dv*8 + (j^(dv&7));
// P (per-wave) block(m,j) at m*8 + (j^(m&7)).  All MFMA-operand
// ds_read_b128 then hit 2-way banks (free).
// ---------------------------------------------------------------------------
__global__ __launch_bounds__(256) void mla_fwd_kernel(
    const float* __restrict__ q_nope, const float* __restrict__ q_pe,
    const __bf16* __restrict__ Kbf, const __bf16* __restrict__ Vtb,
    const float2* __restrict__ tab,
    float* __restrict__ out_o, float* __restrict__ out_lse) {
  __shared__ __bf16 Kl[BN * DQK];       // 24576 B
  __shared__ __bf16 Vl[DVDIM * BN];     // 16384 B
  __shared__ __bf16 Pl[4 * 16 * BN];    //  8192 B   -> 48 KB total

  const int bx = blockIdx.x, h = blockIdx.y, b = blockIdx.z;
  const int tid = threadIdx.x;
  const int w = tid >> 6, lane = tid & 63;
  const int col = lane & 15, quad = lane >> 4;
  const int sw = col & 7;
  const int e0 = quad ^ sw, e1 = (quad + 4) ^ sw;   // swizzled block slots
  const int wo = w * 512;                           // per-wave LDS block base (elems/8*... = blocks*8)

  const __bf16* Kslab = Kbf + (size_t)(b * NH + h) * SEQ * DQK;
  const __bf16* Vslab = Vtb + (size_t)(b * NH + h) * DVDIM * SEQ;

  // staging source offsets (constant across k-iterations)
  int kofs[6];
#pragma unroll
  for (int r = 0; r < 6; ++r) {
    int L = r * 256 + tid;                 // linear 16B block 0..1535
    int n = L / 24, jj = L - n * 24;
    int jsrc = (jj & ~7) | ((jj & 7) ^ (n & 7));
    kofs[r] = n * DQK + jsrc * 8;
  }
  int vofs[4];
#pragma unroll
  for (int r = 0; r < 4; ++r) {
    int L = r * 256 + tid;                 // 0..1023
    int dv = L >> 3, jj = L & 7;
    vofs[r] = dv * SEQ + (jj ^ (dv & 7)) * 8;
  }

  const float kSL2 = 0.07216878364870322f * 1.4426950408889634f; // 192^-.5*log2e

  for (int half = 0; half < 2; ++half) {
    const int qt = half ? bx : (31 - bx);
    const int qb = qt * BM;
    const int mrow = qb + w * 16 + col;

    // ---- Q fragments (A-layout: A[m=lane&15][k=quad*8+j]); rope chunks 4,5
    const float* qn = q_nope + (size_t)((b * SEQ + mrow) * NH + h) * DNOPE;
    const float* qp = q_pe   + (size_t)((b * SEQ + mrow) * NH + h) * DROT;
    bf16x8_t qfrag[6];
#pragma unroll
    for (int c = 0; c < 4; ++c) {
      const float* p = qn + c * 32 + quad * 8;
      float4 a = *(const float4*)p;
      float4 bq = *(const float4*)(p + 4);
      bf16x8_t f;
      f[0]=(__bf16)a.x;  f[1]=(__bf16)a.y;  f[2]=(__bf16)a.z;  f[3]=(__bf16)a.w;
      f[4]=(__bf16)bq.x; f[5]=(__bf16)bq.y; f[6]=(__bf16)bq.z; f[7]=(__bf16)bq.w;
      qfrag[c] = f;
    }
    {
      const float* plo = qp + quad * 8;
      const float* phi = qp + 32 + quad * 8;
      float4 lo0 = *(const float4*)plo;
      float4 lo1 = *(const float4*)(plo + 4);
      float4 hi0 = *(const float4*)phi;
      float4 hi1 = *(const float4*)(phi + 4);
      float xl[8] = {lo0.x,lo0.y,lo0.z,lo0.w,lo1.x,lo1.y,lo1.z,lo1.w};
      float xh[8] = {hi0.x,hi0.y,hi0.z,hi0.w,hi1.x,hi1.y,hi1.z,hi1.w};
      bf16x8_t f4v, f5v;
#pragma unroll
      for (int j = 0; j < 8; ++j) {
        float2 cs = tab[mrow * 32 + quad * 8 + j];
        f4v[j] = (__bf16)(xl[j] * cs.x - xh[j] * cs.y);
        f5v[j] = (__bf16)(xh[j] * cs.x + xl[j] * cs.y);
      }
      qfrag[4] = f4v; qfrag[5] = f5v;
    }

    f32x4_t oacc[8];
#pragma unroll
    for (int i = 0; i < 8; ++i) oacc[i] = (f32x4_t){0.f, 0.f, 0.f, 0.f};
    float m_run[4] = {-INFINITY, -INFINITY, -INFINITY, -INFINITY};
    float l_run[4] = {0.f, 0.f, 0.f, 0.f};

    for (int it = 0; it <= qt; ++it) {
      const int kb = it * BN;
      __syncthreads();                     // prev readers done before overwrite
      const __bf16* Ksrc = Kslab + (size_t)kb * DQK;
#pragma unroll
      for (int r = 0; r < 6; ++r) load_lds16(Ksrc + kofs[r], &Kl[r * 2048 + wo]);
      const __bf16* Vsrc = Vslab + kb;
#pragma unroll
      for (int r = 0; r < 4; ++r) load_lds16(Vsrc + vofs[r], &Vl[r * 2048 + wo]);
      __syncthreads();                     // vmcnt drain + visibility

      // ---- S = Q K^T : 4 n-tiles, 6 K-chunks
      f32x4_t sacc[4];
#pragma unroll
      for (int t = 0; t < 4; ++t) sacc[t] = (f32x4_t){0.f, 0.f, 0.f, 0.f};
#pragma unroll
      for (int t = 0; t < 4; ++t) {
        const __bf16* kr = &Kl[(t * 16 + col) * 24 * 8];
        sacc[t] = __builtin_amdgcn_mfma_f32_16x16x32_bf16(qfrag[0], *(const bf16x8_t*)&kr[e0 * 8], sacc[t], 0, 0, 0);
        sacc[t] = __builtin_amdgcn_mfma_f32_16x16x32_bf16(qfrag[1], *(const bf16x8_t*)&kr[e1 * 8], sacc[t], 0, 0, 0);
        sacc[t] = __builtin_amdgcn_mfma_f32_16x16x32_bf16(qfrag[2], *(const bf16x8_t*)&kr[64 + e0 * 8], sacc[t], 0, 0, 0);
        sacc[t] = __builtin_amdgcn_mfma_f32_16x16x32_bf16(qfrag[3], *(const bf16x8_t*)&kr[64 + e1 * 8], sacc[t], 0, 0, 0);
        sacc[t] = __builtin_amdgcn_mfma_f32_16x16x32_bf16(qfrag[4], *(const bf16x8_t*)&kr[128 + e0 * 8], sacc[t], 0, 0, 0);
        sacc[t] = __builtin_amdgcn_mfma_f32_16x16x32_bf16(qfrag[5], *(const bf16x8_t*)&kr[128 + e1 * 8], sacc[t], 0, 0, 0);
      }

      // ---- online softmax (log2 domain)
      const bool diag = (it == qt);
      float pv[4][4];
      float alpha[4];
#pragma unroll
      for (int r = 0; r < 4; ++r) {
        float mx = -INFINITY;
#pragma unroll
        for (int t = 0; t < 4; ++t) {
          float sv = sacc[t][r] * kSL2;
          if (diag) {
            int nn = kb + t * 16 + col;
            int mm = qb + w * 16 + quad * 4 + r;
            if (nn > mm) sv = -INFINITY;
          }
          pv[t][r] = sv;
          mx = fmaxf(mx, sv);
        }
        mx = fmaxf(mx, __shfl_xor(mx, 1, 64));
        mx = fmaxf(mx, __shfl_xor(mx, 2, 64));
        mx = fmaxf(mx, __shfl_xor(mx, 4, 64));
        mx = fmaxf(mx, __shfl_xor(mx, 8, 64));
        float mnew = fmaxf(m_run[r], mx);
        alpha[r] = exp2f(m_run[r] - mnew);
        m_run[r] = mnew;
        float rs = 0.f;
#pragma unroll
        for (int t = 0; t < 4; ++t) {
          float p = exp2f(pv[t][r] - mnew);
          pv[t][r] = p;
          rs += p;
        }
        rs += __shfl_xor(rs, 1, 64);
        rs += __shfl_xor(rs, 2, 64);
        rs += __shfl_xor(rs, 4, 64);
        rs += __shfl_xor(rs, 8, 64);
        l_run[r] = l_run[r] * alpha[r] + rs;
      }
#pragma unroll
      for (int d = 0; d < 8; ++d) {
        f32x4_t o = oacc[d];
        o[0] *= alpha[0]; o[1] *= alpha[1]; o[2] *= alpha[2]; o[3] *= alpha[3];
        oacc[d] = o;
      }

      // ---- P: C-layout regs -> swizzled per-wave LDS -> A-layout frags
      __bf16* Pw = &Pl[w * 16 * BN];
#pragma unroll
      for (int t = 0; t < 4; ++t)
#pragma unroll
        for (int r = 0; r < 4; ++r) {
          int row = quad * 4 + r;
          int j = t * 2 + (col >> 3);
          Pw[(row * 8 + (j ^ (row & 7))) * 8 + (col & 7)] = (__bf16)pv[t][r];
        }
      bf16x8_t pf0 = *(const bf16x8_t*)&Pw[(col * 8 + e0) * 8];
      bf16x8_t pf1 = *(const bf16x8_t*)&Pw[(col * 8 + e1) * 8];

      // ---- O += P V
#pragma unroll
      for (int d = 0; d < 8; ++d) {
        const __bf16* vr = &Vl[(d * 16 + col) * 64];
        bf16x8_t vf0 = *(const bf16x8_t*)&vr[e0 * 8];
        bf16x8_t vf1 = *(const bf16x8_t*)&vr[e1 * 8];
        oacc[d] = __builtin_amdgcn_mfma_f32_16x16x32_bf16(pf0, vf0, oacc[d], 0, 0, 0);
        oacc[d] = __builtin_amdgcn_mfma_f32_16x16x32_bf16(pf1, vf1, oacc[d], 0, 0, 0);
      }
    }

    // ---- epilogue
    float inv_l[4];
#pragma unroll
    for (int r = 0; r < 4; ++r) inv_l[r] = 1.0f / l_run[r];
#pragma unroll
    for (int d = 0; d < 8; ++d) {
#pragma unroll
      for (int r = 0; r < 4; ++r) {
        int mm = qb + w * 16 + quad * 4 + r;
        out_o[(size_t)((b * SEQ + mm) * NH + h) * DVDIM + d * 16 + col] = oacc[d][r] * inv_l[r];
      }
    }
    if (col < 4) {
      int r = col;
      int mm = qb + w * 16 + quad * 4 + r;
      out_lse[(size_t)(b * SEQ + mm) * NH + h] = m_run[r] + log2f(l_run[r]);
    }
  }
}

// ---------------------------------------------------------------------------
extern "C" void kernel_launch(void* const* d_in, const int* in_sizes, int n_in,
                              void* d_out, int out_size, void* d_ws, size_t ws_size,
                              hipStream_t stream) {
  const float* q_nope = (const float*)d_in[0];
  const float* q_pe   = (const float*)d_in[1];
  const float* k_nope = (const float*)d_in[2];
  const float* k_pe   = (const float*)d_in[3];
  const float* v      = (const float*)d_in[4];
  float* out_o   = (float*)d_out;
  float* out_lse = out_o + (size_t)NB * SEQ * NH * DVDIM;

  float2* tab = (float2*)d_ws;
  __bf16* Kbf = (__bf16*)((char*)d_ws + TAB_BYTES);
  __bf16* Vtb = Kbf + KBF_ELEMS;   // total ws use ~42.5 MB

  trig_kernel<<<dim3(SEQ * 32 / 256), dim3(256), 0, stream>>>(tab);
  prep_k_kernel<<<dim3((unsigned)(KBF_ELEMS / 8 / 256)), dim3(256), 0, stream>>>(
      k_nope, k_pe, tab, Kbf);
  prep_v_kernel<<<dim3(SEQ / 64, NH, NB), dim3(256), 0, stream>>>(v, Vtb);
  mla_fwd_kernel<<<dim3(16, NH, NB), dim3(256), 0, stream>>>(
      q_nope, q_pe, Kbf, Vtb, tab, out_o, out_lse);
}

// Round 3
// 264.168 us; speedup vs baseline: 3.6089x; 1.1980x over previous
//
#include <hip/hip_runtime.h>
#include <hip/hip_bf16.h>
#include <math.h>

// Problem constants (from reference setup_inputs)
#define NB 2
#define SEQ 2048
#define NH 16
#define DNOPE 128
#define DROT 64
#define DVDIM 128
#define DQK 192
#define BM 64
#define BN 64

typedef __bf16 bf16x8_t __attribute__((ext_vector_type(8)));
typedef float f32x4_t __attribute__((ext_vector_type(4)));

// log2(10000)/32 — inv_freq_i = 2^(-i * this); YaRN collapses (SCALING_FACTOR==1)
#define LOG2_BASE_OVER_HALFDIM 0.41524101186092028f
// 192^-0.5 * log2(e), folded into Q at bf16-convert time
#define KSL2 0.10412340175817158f

// ws layout
#define KBF_ELEMS   ((size_t)NB * NH * SEQ * DQK)          // 12,582,912
#define KPREP_BLOCKS 6144                                  // KBF_ELEMS/8/256
#define VPREP_BLOCKS 1024                                  // 32*16*2

// ---------------------------------------------------------------------------
// Fused prep: blocks [0,6144) build K bf16 [b][h][s][192] = concat(k_nope,
// rope(k_pe)); blocks [6144,7168) build V bf16 transposed [b][h][dv][s].
// Trig inline via libm sincosf (full range reduction; args <= ~2047).
// ---------------------------------------------------------------------------
__global__ __launch_bounds__(256) void prep_kernel(
    const float* __restrict__ k_nope, const float* __restrict__ k_pe,
    const float* __restrict__ v, __bf16* __restrict__ Kbf,
    __bf16* __restrict__ Vtb) {
  __shared__ __bf16 T[64][130];
  const int bid = blockIdx.x;
  const int tid = threadIdx.x;
  if (bid < KPREP_BLOCKS) {
    int gid = bid * 256 + tid;                  // 8 elems each
    size_t o8 = (size_t)gid * 8;
    int d0 = (int)(o8 % DQK);                   // multiple of 8
    int rest = (int)(o8 / DQK);                 // (b*16+h)*2048 + s
    int s = rest & (SEQ - 1);
    int bh = rest >> 11;
    int h = bh & (NH - 1), b = bh >> 4;
    bf16x8_t o;
    if (d0 < DNOPE) {
      const float* p = k_nope + ((size_t)((b * SEQ + s) * NH + h)) * DNOPE + d0;
      float4 a = *(const float4*)p;
      float4 c = *(const float4*)(p + 4);
      o[0] = (__bf16)a.x; o[1] = (__bf16)a.y; o[2] = (__bf16)a.z; o[3] = (__bf16)a.w;
      o[4] = (__bf16)c.x; o[5] = (__bf16)c.y; o[6] = (__bf16)c.z; o[7] = (__bf16)c.w;
    } else {
      int dr0 = d0 - DNOPE;
      const float* p = k_pe + (size_t)(b * SEQ + s) * DROT;
#pragma unroll
      for (int j = 0; j < 8; ++j) {
        int dr = dr0 + j;
        int i = dr & 31;
        float invf = exp2f(-LOG2_BASE_OVER_HALFDIM * (float)i);
        float ang = (float)s * invf;
        float sn, cs; sincosf(ang, &sn, &cs);
        float x = p[dr];
        float oth = (dr < 32) ? -p[dr + 32] : p[dr - 32];
        o[j] = (__bf16)(x * cs + oth * sn);
      }
    }
    *(bf16x8_t*)&Kbf[o8] = o;
  } else {
    int vb = bid - KPREP_BLOCKS;
    const int s0 = (vb & 31) * 64, h = (vb >> 5) & (NH - 1), b = vb >> 9;
#pragma unroll
    for (int r = 0; r < 8; ++r) {
      int task = tid + r * 256;                 // 0..2047
      int srow = task >> 5, c4 = (task & 31) * 4;
      const float* p = v + ((size_t)((b * SEQ + s0 + srow) * NH + h)) * DVDIM + c4;
      float4 a = *(const float4*)p;
      T[srow][c4 + 0] = (__bf16)a.x; T[srow][c4 + 1] = (__bf16)a.y;
      T[srow][c4 + 2] = (__bf16)a.z; T[srow][c4 + 3] = (__bf16)a.w;
    }
    __syncthreads();
#pragma unroll
    for (int r = 0; r < 4; ++r) {
      int task = tid + r * 256;                 // 0..1023
      int dv = task >> 3, c8 = (task & 7) * 8;
      bf16x8_t o;
#pragma unroll
      for (int u = 0; u < 8; ++u) o[u] = T[c8 + u][dv];
      *(bf16x8_t*)&Vtb[((size_t)(b * NH + h) * DVDIM + dv) * SEQ + s0 + c8] = o;
    }
  }
}

// ---------------------------------------------------------------------------
// Flash attention fwd. Grid (16, NH, NB): WG bx handles q-tile pair
// {31-bx, bx} -> exactly 33 k-iterations per WG (perfect balance).
// Register-prefetch pipeline: tile it+1 is loaded into VGPRs while tile it
// is computed; LDS commit is 10 ds_write_b128 between the two barriers.
// LDS tiles are 16B blocks with XOR swizzle (all MFMA ds_read_b128 2-way/free).
// l is accumulated by MFMA against a static ones-column tile Vx (flash l
// recurrence == extra output column), killing the per-row sum reduction.
// ---------------------------------------------------------------------------
__global__ __launch_bounds__(256, 2) void mla_fwd_kernel(
    const float* __restrict__ q_nope, const float* __restrict__ q_pe,
    const __bf16* __restrict__ Kbf, const __bf16* __restrict__ Vtb,
    float* __restrict__ out_o, float* __restrict__ out_lse) {
  __shared__ __bf16 Kl[BN * DQK];       // 24576 B
  __shared__ __bf16 Vl[DVDIM * BN];     // 16384 B
  __shared__ __bf16 Pl[4 * 16 * BN];    //  8192 B
  __shared__ __bf16 Vx[16 * 72];        //  2304 B  (ones-column tile)

  const int bx = blockIdx.x, h = blockIdx.y, b = blockIdx.z;
  const int tid = threadIdx.x;
  const int w = tid >> 6, lane = tid & 63;
  const int col = lane & 15, quad = lane >> 4;
  const int swz = col & 7;
  const int e0 = quad ^ swz, e1 = (quad + 4) ^ swz;   // swizzled block slots

  // static ones-column tile: row 0 = ones over 64 keys, rows 1..15 = 0
  for (int i = tid; i < 16 * 72; i += 256)
    Vx[i] = (i < 64) ? (__bf16)1.0f : (__bf16)0.0f;

  const __bf16* Kslab = Kbf + (size_t)(b * NH + h) * SEQ * DQK;
  const __bf16* Vslab = Vtb + (size_t)(b * NH + h) * DVDIM * SEQ;

  // staging source offsets (swizzle folded into global source index)
  int kofs[6];
#pragma unroll
  for (int r = 0; r < 6; ++r) {
    int L = r * 256 + tid;                 // linear 16B block 0..1535
    int n = L / 24, jj = L - n * 24;
    int jsrc = (jj & ~7) | ((jj & 7) ^ (n & 7));
    kofs[r] = n * DQK + jsrc * 8;
  }
  int vofs[4];
#pragma unroll
  for (int r = 0; r < 4; ++r) {
    int L = r * 256 + tid;                 // 0..1023
    int dv = L >> 3, jj = L & 7;
    vofs[r] = dv * SEQ + (jj ^ (dv & 7)) * 8;
  }

  __syncthreads();                         // Vx visible
  const bf16x8_t vxf0 = *(const bf16x8_t*)&Vx[col * 72 + quad * 8];
  const bf16x8_t vxf1 = *(const bf16x8_t*)&Vx[col * 72 + 32 + quad * 8];

  for (int half = 0; half < 2; ++half) {
    const int qt = half ? bx : (31 - bx);
    const int qb = qt * BM;
    const int mrow = qb + w * 16 + col;

    // ---- Q fragments (A-layout: A[m=lane&15][k=quad*8+j]); scale folded in;
    // rope chunks 4,5 computed with inline sincosf (8 calls, once per half).
    const float* qn = q_nope + (size_t)((b * SEQ + mrow) * NH + h) * DNOPE;
    const float* qp = q_pe   + (size_t)((b * SEQ + mrow) * NH + h) * DROT;
    bf16x8_t qfrag[6];
#pragma unroll
    for (int c = 0; c < 4; ++c) {
      const float* p = qn + c * 32 + quad * 8;
      float4 a = *(const float4*)p;
      float4 bq = *(const float4*)(p + 4);
      bf16x8_t f;
      f[0]=(__bf16)(a.x*KSL2);  f[1]=(__bf16)(a.y*KSL2);
      f[2]=(__bf16)(a.z*KSL2);  f[3]=(__bf16)(a.w*KSL2);
      f[4]=(__bf16)(bq.x*KSL2); f[5]=(__bf16)(bq.y*KSL2);
      f[6]=(__bf16)(bq.z*KSL2); f[7]=(__bf16)(bq.w*KSL2);
      qfrag[c] = f;
    }
    {
      const float* plo = qp + quad * 8;
      const float* phi = qp + 32 + quad * 8;
      float4 lo0 = *(const float4*)plo;
      float4 lo1 = *(const float4*)(plo + 4);
      float4 hi0 = *(const float4*)phi;
      float4 hi1 = *(const float4*)(phi + 4);
      float xl[8] = {lo0.x,lo0.y,lo0.z,lo0.w,lo1.x,lo1.y,lo1.z,lo1.w};
      float xh[8] = {hi0.x,hi0.y,hi0.z,hi0.w,hi1.x,hi1.y,hi1.z,hi1.w};
      bf16x8_t f4v, f5v;
#pragma unroll
      for (int j = 0; j < 8; ++j) {
        int i = quad * 8 + j;
        float invf = exp2f(-LOG2_BASE_OVER_HALFDIM * (float)i);
        float ang = (float)mrow * invf;
        float sn, cs; sincosf(ang, &sn, &cs);
        f4v[j] = (__bf16)((xl[j] * cs - xh[j] * sn) * KSL2);
        f5v[j] = (__bf16)((xh[j] * cs + xl[j] * sn) * KSL2);
      }
      qfrag[4] = f4v; qfrag[5] = f5v;
    }

    f32x4_t oacc[8];
#pragma unroll
    for (int i = 0; i < 8; ++i) oacc[i] = (f32x4_t){0.f, 0.f, 0.f, 0.f};
    f32x4_t lacc = (f32x4_t){0.f, 0.f, 0.f, 0.f};
    float m_run[4] = {-INFINITY, -INFINITY, -INFINITY, -INFINITY};

    // ---- prologue: load tile 0 into registers
    bf16x8_t Kreg[6], Vreg[4];
#pragma unroll
    for (int r = 0; r < 6; ++r) Kreg[r] = *(const bf16x8_t*)(Kslab + kofs[r]);
#pragma unroll
    for (int r = 0; r < 4; ++r) Vreg[r] = *(const bf16x8_t*)(Vslab + vofs[r]);

    for (int it = 0; it <= qt; ++it) {
      __syncthreads();                     // prev readers done before overwrite
      // commit registers to LDS (10 x ds_write_b128, conflict-free)
#pragma unroll
      for (int r = 0; r < 6; ++r) *(bf16x8_t*)&Kl[(r * 256 + tid) * 8] = Kreg[r];
#pragma unroll
      for (int r = 0; r < 4; ++r) *(bf16x8_t*)&Vl[(r * 256 + tid) * 8] = Vreg[r];
      __syncthreads();                     // writes visible
      // prefetch tile it+1 (latency overlaps the whole compute phase)
      if (it < qt) {
        const __bf16* Ksrc = Kslab + (size_t)(it + 1) * BN * DQK;
        const __bf16* Vsrc = Vslab + (it + 1) * BN;
#pragma unroll
        for (int r = 0; r < 6; ++r) Kreg[r] = *(const bf16x8_t*)(Ksrc + kofs[r]);
#pragma unroll
        for (int r = 0; r < 4; ++r) Vreg[r] = *(const bf16x8_t*)(Vsrc + vofs[r]);
      }

      // ---- S = Q K^T : 4 n-tiles, 6 K-chunks (pre-scaled, log2 domain)
      f32x4_t sacc[4];
#pragma unroll
      for (int t = 0; t < 4; ++t) sacc[t] = (f32x4_t){0.f, 0.f, 0.f, 0.f};
#pragma unroll
      for (int t = 0; t < 4; ++t) {
        const __bf16* kr = &Kl[(t * 16 + col) * 24 * 8];
        sacc[t] = __builtin_amdgcn_mfma_f32_16x16x32_bf16(qfrag[0], *(const bf16x8_t*)&kr[e0 * 8], sacc[t], 0, 0, 0);
        sacc[t] = __builtin_amdgcn_mfma_f32_16x16x32_bf16(qfrag[1], *(const bf16x8_t*)&kr[e1 * 8], sacc[t], 0, 0, 0);
        sacc[t] = __builtin_amdgcn_mfma_f32_16x16x32_bf16(qfrag[2], *(const bf16x8_t*)&kr[64 + e0 * 8], sacc[t], 0, 0, 0);
        sacc[t] = __builtin_amdgcn_mfma_f32_16x16x32_bf16(qfrag[3], *(const bf16x8_t*)&kr[64 + e1 * 8], sacc[t], 0, 0, 0);
        sacc[t] = __builtin_amdgcn_mfma_f32_16x16x32_bf16(qfrag[4], *(const bf16x8_t*)&kr[128 + e0 * 8], sacc[t], 0, 0, 0);
        sacc[t] = __builtin_amdgcn_mfma_f32_16x16x32_bf16(qfrag[5], *(const bf16x8_t*)&kr[128 + e1 * 8], sacc[t], 0, 0, 0);
      }

      // ---- online softmax (log2 domain; only the max needs a reduction)
      const bool diag = (it == qt);
      float pv[4][4];
      float alpha[4];
#pragma unroll
      for (int r = 0; r < 4; ++r) {
        float mx = -INFINITY;
#pragma unroll
        for (int t = 0; t < 4; ++t) {
          float sv = sacc[t][r];
          if (diag) {
            int nn = (qt << 6) + t * 16 + col;
            int mm = qb + w * 16 + quad * 4 + r;
            if (nn > mm) sv = -INFINITY;
          }
          pv[t][r] = sv;
          mx = fmaxf(mx, sv);
        }
        mx = fmaxf(mx, __shfl_xor(mx, 1, 64));
        mx = fmaxf(mx, __shfl_xor(mx, 2, 64));
        mx = fmaxf(mx, __shfl_xor(mx, 4, 64));
        mx = fmaxf(mx, __shfl_xor(mx, 8, 64));
        float mnew = fmaxf(m_run[r], mx);
        alpha[r] = exp2f(m_run[r] - mnew);
        m_run[r] = mnew;
#pragma unroll
        for (int t = 0; t < 4; ++t) pv[t][r] = exp2f(pv[t][r] - mnew);
      }
#pragma unroll
      for (int d = 0; d < 8; ++d) {
        f32x4_t o = oacc[d];
        o[0] *= alpha[0]; o[1] *= alpha[1]; o[2] *= alpha[2]; o[3] *= alpha[3];
        oacc[d] = o;
      }
      lacc[0] *= alpha[0]; lacc[1] *= alpha[1];
      lacc[2] *= alpha[2]; lacc[3] *= alpha[3];

      // ---- P: C-layout regs -> swizzled per-wave LDS -> A-layout frags
      __bf16* Pw = &Pl[w * 16 * BN];
#pragma unroll
      for (int t = 0; t < 4; ++t)
#pragma unroll
        for (int r = 0; r < 4; ++r) {
          int row = quad * 4 + r;
          int j = t * 2 + (col >> 3);
          Pw[(row * 8 + (j ^ (row & 7))) * 8 + (col & 7)] = (__bf16)pv[t][r];
        }
      bf16x8_t pf0 = *(const bf16x8_t*)&Pw[(col * 8 + e0) * 8];
      bf16x8_t pf1 = *(const bf16x8_t*)&Pw[(col * 8 + e1) * 8];

      // ---- O += P V ; l += P * ones (extra static tile)
#pragma unroll
      for (int d = 0; d < 8; ++d) {
        const __bf16* vr = &Vl[(d * 16 + col) * 64];
        bf16x8_t vf0 = *(const bf16x8_t*)&vr[e0 * 8];
        bf16x8_t vf1 = *(const bf16x8_t*)&vr[e1 * 8];
        oacc[d] = __builtin_amdgcn_mfma_f32_16x16x32_bf16(pf0, vf0, oacc[d], 0, 0, 0);
        oacc[d] = __builtin_amdgcn_mfma_f32_16x16x32_bf16(pf1, vf1, oacc[d], 0, 0, 0);
      }
      lacc = __builtin_amdgcn_mfma_f32_16x16x32_bf16(pf0, vxf0, lacc, 0, 0, 0);
      lacc = __builtin_amdgcn_mfma_f32_16x16x32_bf16(pf1, vxf1, lacc, 0, 0, 0);
    }

    // ---- epilogue: broadcast l from col-0 lanes, normalize, store
    float lr[4];
#pragma unroll
    for (int r = 0; r < 4; ++r) lr[r] = __shfl(lacc[r], lane & 48, 64);
    float inv_l[4];
#pragma unroll
    for (int r = 0; r < 4; ++r) inv_l[r] = 1.0f / lr[r];
#pragma unroll
    for (int d = 0; d < 8; ++d) {
#pragma unroll
      for (int r = 0; r < 4; ++r) {
        int mm = qb + w * 16 + quad * 4 + r;
        out_o[(size_t)((b * SEQ + mm) * NH + h) * DVDIM + d * 16 + col] = oacc[d][r] * inv_l[r];
      }
    }
    if (col < 4) {
      int r = col;
      int mm = qb + w * 16 + quad * 4 + r;
      out_lse[(size_t)(b * SEQ + mm) * NH + h] = m_run[r] + log2f(lr[r]);
    }
  }
}

// ---------------------------------------------------------------------------
extern "C" void kernel_launch(void* const* d_in, const int* in_sizes, int n_in,
                              void* d_out, int out_size, void* d_ws, size_t ws_size,
                              hipStream_t stream) {
  const float* q_nope = (const float*)d_in[0];
  const float* q_pe   = (const float*)d_in[1];
  const float* k_nope = (const float*)d_in[2];
  const float* k_pe   = (const float*)d_in[3];
  const float* v      = (const float*)d_in[4];
  float* out_o   = (float*)d_out;
  float* out_lse = out_o + (size_t)NB * SEQ * NH * DVDIM;

  __bf16* Kbf = (__bf16*)d_ws;
  __bf16* Vtb = Kbf + KBF_ELEMS;   // total ws use ~40 MB

  prep_kernel<<<dim3(KPREP_BLOCKS + VPREP_BLOCKS), dim3(256), 0, stream>>>(
      k_nope, k_pe, v, Kbf, Vtb);
  mla_fwd_kernel<<<dim3(16, NH, NB), dim3(256), 0, stream>>>(
      q_nope, q_pe, Kbf, Vtb, out_o, out_lse);
}